// Round 20
// baseline (4771.331 us; speedup 1.0000x reference)
//
#include <hip/hip_runtime.h>
#include <math.h>

// Problem constants
#define HH   300
#define H3   900
#define MMOL 256
#define LATM 128
#define AA   32769        // 1 + 256*128
#define NBB  6
#define BBND 131073       // 1 + 4*256*128
#define AFD  133
#define BFD  147
#define MLR  (MMOL * LATM)   // 32768

static __device__ __forceinline__ float sigm(float x) { return 1.0f / (1.0f + expf(-x)); }

typedef __attribute__((ext_vector_type(8))) short bfrag;   // 8 bf16
typedef __attribute__((ext_vector_type(4))) float ffrag;   // 4 f32

static __device__ __forceinline__ unsigned short f2bf(float x) {
    unsigned u = __float_as_uint(x);
    u += 0x7FFF + ((u >> 16) & 1);
    return (unsigned short)(u >> 16);
}
static __device__ __forceinline__ float bf2f(unsigned short h) {
    return __uint_as_float(((unsigned)h) << 16);
}

// ---------------------------------------------------------------------------
// split_w: W[N rows, k in koff..koff+K) of ldw-strided fp32 -> 3 bf16 planes
// ---------------------------------------------------------------------------
__global__ void split_w(const float* __restrict__ W, int ldw, int koff, int N, int K,
                        int Npad, int Kpad, unsigned short* __restrict__ planes)
{
    long tot = (long)Npad * Kpad;
    long idx = (long)blockIdx.x * blockDim.x + threadIdx.x;
    if (idx >= tot) return;
    int n = (int)(idx / Kpad), k = (int)(idx - (long)n * Kpad);
    float x = (n < N && k < K) ? W[(long)n * ldw + koff + k] : 0.0f;
    unsigned short h = f2bf(x); float r1 = x - bf2f(h);
    unsigned short m = f2bf(r1); float r2 = r1 - bf2f(m);
    planes[idx] = h;
    planes[tot + idx] = m;
    planes[2 * tot + idx] = f2bf(r2);
}

// ---------------------------------------------------------------------------
// mfma2: fp32-equivalent GEMM, 3-way bf16 split, 6 products (validated order).
// ---------------------------------------------------------------------------
template<int NCT, bool RELU, bool BIAS, bool ACCUM>
__global__ __launch_bounds__(256)
void mfma2(const float* __restrict__ X, int ldx,
           const unsigned short* __restrict__ Wpl, int wrow0, int Nalloc, int Kpad,
           const float* __restrict__ Bias, float* __restrict__ C, int ldc,
           int rows, int N, int K)
{
    __shared__ __align__(16) unsigned short Xp[3][64][40];
    const int tid  = threadIdx.x;
    const int lane = tid & 63;
    const int wv   = tid >> 6;
    const int row0 = blockIdx.x * 64;
    const int colbase = blockIdx.y * (NCT * 64);
    const int wr   = (wv >> 1) * 32;
    const int wc   = (wv & 1) * 32;
    const int sr   = tid >> 2;
    const int sk   = (tid & 3) * 8;
    const long PS  = (long)Nalloc * Kpad;

    ffrag acc[NCT][2][2];
#pragma unroll
    for (int c = 0; c < NCT; ++c)
#pragma unroll
        for (int i = 0; i < 2; ++i)
#pragma unroll
            for (int j = 0; j < 2; ++j) acc[c][i][j] = (ffrag){0.f, 0.f, 0.f, 0.f};

    const int fr = lane & 15;
    const int kb = (lane >> 4) * 8;

    for (int k0 = 0; k0 < K; k0 += 32) {
        {
            unsigned short h8[8], m8[8], l8[8];
            int gr = row0 + sr;
#pragma unroll
            for (int i = 0; i < 8; ++i) {
                int k = k0 + sk + i;
                float x = (gr < rows && k < K) ? X[(long)gr * ldx + k] : 0.0f;
                unsigned short h = f2bf(x); float r1 = x - bf2f(h);
                unsigned short m = f2bf(r1); float r2 = r1 - bf2f(m);
                h8[i] = h; m8[i] = m; l8[i] = f2bf(r2);
            }
            *(bfrag*)&Xp[0][sr][sk] = *(bfrag*)h8;
            *(bfrag*)&Xp[1][sr][sk] = *(bfrag*)m8;
            *(bfrag*)&Xp[2][sr][sk] = *(bfrag*)l8;
        }
        __syncthreads();

        bfrag ax[3][2];
#pragma unroll
        for (int s = 0; s < 3; ++s)
#pragma unroll
            for (int t2 = 0; t2 < 2; ++t2)
                ax[s][t2] = *(const bfrag*)&Xp[s][wr + t2 * 16 + fr][kb];

#pragma unroll
        for (int ct = 0; ct < NCT; ++ct) {
            int prow0 = wrow0 + colbase + ct * 64 + wc + fr;
            int pr[2];
            pr[0] = prow0;              if (pr[0] > Nalloc - 1) pr[0] = Nalloc - 1;
            pr[1] = prow0 + 16;         if (pr[1] > Nalloc - 1) pr[1] = Nalloc - 1;
            bfrag bx[3][2];
#pragma unroll
            for (int s = 0; s < 3; ++s)
#pragma unroll
                for (int t2 = 0; t2 < 2; ++t2)
                    bx[s][t2] = *(const bfrag*)(Wpl + (long)s * PS + (long)pr[t2] * Kpad + k0 + kb);

#pragma unroll
            for (int st = 0; st < 2; ++st)
#pragma unroll
                for (int c2 = 0; c2 < 2; ++c2) {
                    ffrag a = acc[ct][st][c2];
                    a = __builtin_amdgcn_mfma_f32_16x16x32_bf16(ax[1][st], bx[1][c2], a, 0, 0, 0); // mM
                    a = __builtin_amdgcn_mfma_f32_16x16x32_bf16(ax[0][st], bx[2][c2], a, 0, 0, 0); // hL
                    a = __builtin_amdgcn_mfma_f32_16x16x32_bf16(ax[2][st], bx[0][c2], a, 0, 0, 0); // lH
                    a = __builtin_amdgcn_mfma_f32_16x16x32_bf16(ax[0][st], bx[1][c2], a, 0, 0, 0); // hM
                    a = __builtin_amdgcn_mfma_f32_16x16x32_bf16(ax[1][st], bx[0][c2], a, 0, 0, 0); // mH
                    a = __builtin_amdgcn_mfma_f32_16x16x32_bf16(ax[0][st], bx[0][c2], a, 0, 0, 0); // hH
                    acc[ct][st][c2] = a;
                }
        }
        __syncthreads();
    }

    const int orow = (lane >> 4) * 4;
    const int ocol = lane & 15;
#pragma unroll
    for (int ct = 0; ct < NCT; ++ct)
#pragma unroll
        for (int st = 0; st < 2; ++st)
#pragma unroll
            for (int c2 = 0; c2 < 2; ++c2)
#pragma unroll
                for (int rg = 0; rg < 4; ++rg) {
                    int gr = row0 + wr + st * 16 + orow + rg;
                    int gc = colbase + ct * 64 + wc + c2 * 16 + ocol;
                    if (gr < rows && gc < N) {
                        float v = acc[ct][st][c2][rg];
                        if (BIAS)  v += Bias[gc];
                        if (ACCUM) v += C[(long)gr * ldc + gc];
                        if (RELU)  v = fmaxf(v, 0.0f);
                        C[(long)gr * ldc + gc] = v;
                    }
                }
}

// ---------------------------------------------------------------------------
// mfma_vw: merged Vw (lo -> S, hi -> P in place), bit-identical split/order.
// ---------------------------------------------------------------------------
__global__ __launch_bounds__(256)
void mfma_vw(const float* __restrict__ Xp_, const unsigned short* __restrict__ Wpl,
             float* __restrict__ S, float* __restrict__ P, int rows)
{
    const int NCT = 5;
    __shared__ __align__(16) unsigned short Xp[3][64][40];
    const int tid  = threadIdx.x;
    const int lane = tid & 63;
    const int wv   = tid >> 6;
    const int row0 = blockIdx.x * 64;
    const int wr   = (wv >> 1) * 32;
    const int wc   = (wv & 1) * 32;
    const int sr   = tid >> 2;
    const int sk   = (tid & 3) * 8;
    const long PS  = (long)320 * 320;

    ffrag acc[NCT][2][2];
#pragma unroll
    for (int c = 0; c < NCT; ++c)
#pragma unroll
        for (int i = 0; i < 2; ++i)
#pragma unroll
            for (int j = 0; j < 2; ++j) acc[c][i][j] = (ffrag){0.f, 0.f, 0.f, 0.f};

    const int fr = lane & 15;
    const int kb = (lane >> 4) * 8;

    for (int k0 = 0; k0 < 300; k0 += 32) {
        {
            unsigned short h8[8], m8[8], l8[8];
            int gr = row0 + sr;
#pragma unroll
            for (int i = 0; i < 8; ++i) {
                int k = k0 + sk + i;
                float x = (gr < rows && k < 300) ? Xp_[(long)gr * 300 + k] : 0.0f;
                unsigned short h = f2bf(x); float r1 = x - bf2f(h);
                unsigned short m = f2bf(r1); float r2 = r1 - bf2f(m);
                h8[i] = h; m8[i] = m; l8[i] = f2bf(r2);
            }
            *(bfrag*)&Xp[0][sr][sk] = *(bfrag*)h8;
            *(bfrag*)&Xp[1][sr][sk] = *(bfrag*)m8;
            *(bfrag*)&Xp[2][sr][sk] = *(bfrag*)l8;
        }
        __syncthreads();

        bfrag ax[3][2];
#pragma unroll
        for (int s = 0; s < 3; ++s)
#pragma unroll
            for (int t2 = 0; t2 < 2; ++t2)
                ax[s][t2] = *(const bfrag*)&Xp[s][wr + t2 * 16 + fr][kb];

#pragma unroll
        for (int ct = 0; ct < NCT; ++ct) {
            int prow0 = ct * 64 + wc + fr;
            int pr[2];
            pr[0] = prow0;       if (pr[0] > 319) pr[0] = 319;
            pr[1] = prow0 + 16;  if (pr[1] > 319) pr[1] = 319;
            bfrag bx[3][2];
#pragma unroll
            for (int s = 0; s < 3; ++s)
#pragma unroll
                for (int t2 = 0; t2 < 2; ++t2)
                    bx[s][t2] = *(const bfrag*)(Wpl + (long)s * PS + (long)pr[t2] * 320 + k0 + kb);

#pragma unroll
            for (int st = 0; st < 2; ++st)
#pragma unroll
                for (int c2 = 0; c2 < 2; ++c2) {
                    ffrag a = acc[ct][st][c2];
                    a = __builtin_amdgcn_mfma_f32_16x16x32_bf16(ax[1][st], bx[1][c2], a, 0, 0, 0);
                    a = __builtin_amdgcn_mfma_f32_16x16x32_bf16(ax[0][st], bx[2][c2], a, 0, 0, 0);
                    a = __builtin_amdgcn_mfma_f32_16x16x32_bf16(ax[2][st], bx[0][c2], a, 0, 0, 0);
                    a = __builtin_amdgcn_mfma_f32_16x16x32_bf16(ax[0][st], bx[1][c2], a, 0, 0, 0);
                    a = __builtin_amdgcn_mfma_f32_16x16x32_bf16(ax[1][st], bx[0][c2], a, 0, 0, 0);
                    a = __builtin_amdgcn_mfma_f32_16x16x32_bf16(ax[0][st], bx[0][c2], a, 0, 0, 0);
                    acc[ct][st][c2] = a;
                }
        }
        __syncthreads();
    }

    const int orow = (lane >> 4) * 4;
    const int ocol = lane & 15;
#pragma unroll
    for (int ct = 0; ct < NCT; ++ct)
#pragma unroll
        for (int st = 0; st < 2; ++st)
#pragma unroll
            for (int c2 = 0; c2 < 2; ++c2)
#pragma unroll
                for (int rg = 0; rg < 4; ++rg) {
                    int gr = row0 + wr + st * 16 + orow + rg;
                    int gc = ct * 64 + wc + c2 * 16 + ocol;
                    if (gr < rows && gc < 300) {
                        float v = acc[ct][st][c2][rg];
                        if (gc < 150) S[(long)gr * 150 + gc] = v;
                        else          P[(long)gr * 300 + (gc - 150)] = v;
                    }
                }
}

// ---------------------------------------------------------------------------
// mfma_bond: mfma2 core (X = f_bonds, K=147) + gather epilogue.
// ---------------------------------------------------------------------------
template<int NCT>
__global__ __launch_bounds__(256)
void mfma_bond(const float* __restrict__ X, int ldx,
               const unsigned short* __restrict__ Wpl, int wrow0, int Nalloc, int Kpad,
               const float* __restrict__ Th, const float* __restrict__ Vsrc, int vstride,
               const int* __restrict__ b2a, const int* __restrict__ b2revb,
               float* __restrict__ P, int c0, int rows, int N, int K)
{
    __shared__ __align__(16) unsigned short Xp[3][64][40];
    const int tid  = threadIdx.x;
    const int lane = tid & 63;
    const int wv   = tid >> 6;
    const int row0 = blockIdx.x * 64;
    const int colbase = blockIdx.y * (NCT * 64);
    const int wr   = (wv >> 1) * 32;
    const int wc   = (wv & 1) * 32;
    const int sr   = tid >> 2;
    const int sk   = (tid & 3) * 8;
    const long PS  = (long)Nalloc * Kpad;

    ffrag acc[NCT][2][2];
#pragma unroll
    for (int c = 0; c < NCT; ++c)
#pragma unroll
        for (int i = 0; i < 2; ++i)
#pragma unroll
            for (int j = 0; j < 2; ++j) acc[c][i][j] = (ffrag){0.f, 0.f, 0.f, 0.f};

    const int fr = lane & 15;
    const int kb = (lane >> 4) * 8;

    for (int k0 = 0; k0 < K; k0 += 32) {
        {
            unsigned short h8[8], m8[8], l8[8];
            int gr = row0 + sr;
#pragma unroll
            for (int i = 0; i < 8; ++i) {
                int k = k0 + sk + i;
                float x = (gr < rows && k < K) ? X[(long)gr * ldx + k] : 0.0f;
                unsigned short h = f2bf(x); float r1 = x - bf2f(h);
                unsigned short m = f2bf(r1); float r2 = r1 - bf2f(m);
                h8[i] = h; m8[i] = m; l8[i] = f2bf(r2);
            }
            *(bfrag*)&Xp[0][sr][sk] = *(bfrag*)h8;
            *(bfrag*)&Xp[1][sr][sk] = *(bfrag*)m8;
            *(bfrag*)&Xp[2][sr][sk] = *(bfrag*)l8;
        }
        __syncthreads();

        bfrag ax[3][2];
#pragma unroll
        for (int s = 0; s < 3; ++s)
#pragma unroll
            for (int t2 = 0; t2 < 2; ++t2)
                ax[s][t2] = *(const bfrag*)&Xp[s][wr + t2 * 16 + fr][kb];

#pragma unroll
        for (int ct = 0; ct < NCT; ++ct) {
            int prow0 = wrow0 + colbase + ct * 64 + wc + fr;
            int pr[2];
            pr[0] = prow0;              if (pr[0] > Nalloc - 1) pr[0] = Nalloc - 1;
            pr[1] = prow0 + 16;         if (pr[1] > Nalloc - 1) pr[1] = Nalloc - 1;
            bfrag bx[3][2];
#pragma unroll
            for (int s = 0; s < 3; ++s)
#pragma unroll
                for (int t2 = 0; t2 < 2; ++t2)
                    bx[s][t2] = *(const bfrag*)(Wpl + (long)s * PS + (long)pr[t2] * Kpad + k0 + kb);

#pragma unroll
            for (int st = 0; st < 2; ++st)
#pragma unroll
                for (int c2 = 0; c2 < 2; ++c2) {
                    ffrag a = acc[ct][st][c2];
                    a = __builtin_amdgcn_mfma_f32_16x16x32_bf16(ax[1][st], bx[1][c2], a, 0, 0, 0);
                    a = __builtin_amdgcn_mfma_f32_16x16x32_bf16(ax[0][st], bx[2][c2], a, 0, 0, 0);
                    a = __builtin_amdgcn_mfma_f32_16x16x32_bf16(ax[2][st], bx[0][c2], a, 0, 0, 0);
                    a = __builtin_amdgcn_mfma_f32_16x16x32_bf16(ax[0][st], bx[1][c2], a, 0, 0, 0);
                    a = __builtin_amdgcn_mfma_f32_16x16x32_bf16(ax[1][st], bx[0][c2], a, 0, 0, 0);
                    a = __builtin_amdgcn_mfma_f32_16x16x32_bf16(ax[0][st], bx[0][c2], a, 0, 0, 0);
                    acc[ct][st][c2] = a;
                }
        }
        __syncthreads();
    }

    const int orow = (lane >> 4) * 4;
    const int ocol = lane & 15;
#pragma unroll
    for (int st = 0; st < 2; ++st)
#pragma unroll
        for (int rg = 0; rg < 4; ++rg) {
            int gr = row0 + wr + st * 16 + orow + rg;
            if (gr >= rows) continue;
            int a  = b2a[gr];
            int rv = b2revb[gr];
#pragma unroll
            for (int ct = 0; ct < NCT; ++ct)
#pragma unroll
                for (int c2 = 0; c2 < 2; ++c2) {
                    int gc = colbase + ct * 64 + wc + c2 * 16 + ocol;
                    if (gc >= N) continue;
                    float ib = fmaxf(acc[ct][st][c2][rg], 0.0f);
                    float v  = ib + Th[(long)a * 150 + gc] - Vsrc[(long)rv * vstride + gc];
                    P[(long)gr * 300 + c0 + gc] = fmaxf(v, 0.0f);
                }
        }
}

// transposeQ: Whh[900][300] -> WQ[(k/4)][n][4]
__global__ void transposeQ(const float* __restrict__ in, float* __restrict__ out)
{
    long idx = (long)blockIdx.x * blockDim.x + threadIdx.x;
    if (idx >= 270000) return;
    int n = (int)(idx / 300), k = (int)(idx - (long)n * 300);
    out[(long)(k >> 2) * 3600 + n * 4 + (k & 3)] = in[idx];
}

template<bool ADD>
__global__ void aggregate(const float* __restrict__ mb, const int* __restrict__ a2b,
                          float* __restrict__ dst)
{
    long idx = (long)blockIdx.x * blockDim.x + threadIdx.x;
    if (idx >= (long)AA * HH) return;
    int a = (int)(idx / HH);
    int h = (int)(idx - (long)a * HH);
    const int* nb = a2b + (long)a * NBB;
    float s = 0.0f, mx = -INFINITY;
#pragma unroll
    for (int i = 0; i < NBB; ++i) {
        float v = mb[(long)nb[i] * HH + h];
        s += v;
        mx = fmaxf(mx, v);
    }
    float r = s * mx;
    if (ADD) r += dst[idx];
    dst[idx] = r;
}

__global__ void msgx_kernel(const float* __restrict__ node, const float* __restrict__ gbias,
                            float* __restrict__ msgx)
{
    long idx = (long)blockIdx.x * blockDim.x + threadIdx.x;
    if (idx >= (long)MLR * HH) return;
    int h = (int)(idx % HH);
    msgx[idx] = fmaxf(node[idx + HH] + gbias[h], 0.0f);
}

__global__ void h0_kernel(const float* __restrict__ node, float* __restrict__ hf)
{
    int idx = blockIdx.x * blockDim.x + threadIdx.x;
    if (idx >= MMOL * HH) return;
    int m = idx / HH;
    int h = idx - m * HH;
    long base = (long)(1 + m * LATM) * HH + h;
    float mx = -INFINITY;
    for (int t = 0; t < LATM; ++t) mx = fmaxf(mx, node[base + (long)t * HH]);
    hf[idx] = mx;
}

// ---------------------------------------------------------------------------
// GRU scan v5: as proven v3q (256 blocks, 2 mols, XCD-pinned dirs, WQ
// interleaved weights), plus gi-prefetch: the 124 idle threads (tid>=900)
// load the step's gi rows into LDS during phase 1, so phase 2 reads LDS
// instead of paying global latency after the barrier. Bit-identical values.
// ---------------------------------------------------------------------------
__global__ __launch_bounds__(1024)
void gru_scan3(const float* __restrict__ WQ_f, const float* __restrict__ bhh_f,
               const float* __restrict__ WQ_b, const float* __restrict__ bhh_b,
               const float* __restrict__ h0, float* __restrict__ gi_f,
               float* __restrict__ gi_b)
{
    const int bid  = blockIdx.x;
    const int xcd  = bid & 7;
    const int dir  = (xcd >= 4) ? 1 : 0;
    const int rank = (bid >> 3) * 4 + (xcd & 3);
    const int m0   = rank * 2;
    const float* WQ  = dir ? WQ_b  : WQ_f;
    const float* bhh = dir ? bhh_b : bhh_f;
    float*       gi  = dir ? gi_b  : gi_f;
    const int tid = threadIdx.x;

    __shared__ float hs[2][304];
    __shared__ float ghs[2][H3];
    __shared__ float gis[2][H3];    // prefetched gi[t] (both mols)

    float bb = (tid < H3) ? bhh[tid] : 0.0f;

    for (int i = tid; i < 150; i += 1024) {
        int mm = i / 75, q = (i - mm * 75) * 4;
        *(float4*)&hs[mm][q] = *(const float4*)&h0[(long)(m0 + mm) * HH + q];
    }
    __syncthreads();

    for (int s = 0; s < LATM; ++s) {
        const int t = dir ? (LATM - 1 - s) : s;

        if (tid < H3) {
            // phase 1: gh for 900 gate units x 2 mols (the L2 weight stream)
            float a0 = 0.0f, a1 = 0.0f;
            const float* wq = WQ + (long)tid * 4;
#pragma unroll 4
            for (int k0 = 0; k0 < HH; k0 += 4) {
                float4 w = *(const float4*)wq;
                wq += 3600;
                float4 h0v = *(const float4*)&hs[0][k0];
                float4 h1v = *(const float4*)&hs[1][k0];
                a0 += h0v.x * w.x + h0v.y * w.y + h0v.z * w.z + h0v.w * w.w;
                a1 += h1v.x * w.x + h1v.y * w.y + h1v.z * w.z + h1v.w * w.w;
            }
            ghs[0][tid] = a0 + bb;
            ghs[1][tid] = a1 + bb;
        } else {
            // idle lanes prefetch gi[t] rows (2 x 900 floats) into LDS.
            // Safe: gi[t] cols 0..299 are written only in phase 2 of this
            // same step (after the barrier) — read-before-write.
            for (int i = tid - 900; i < 450; i += 124) {
                int mm = (i < 225) ? 0 : 1;
                int q  = (i - mm * 225) * 4;
                long row = (long)(m0 + mm) * LATM + t;
                *(float4*)&gis[mm][q] = *(const float4*)&gi[row * H3 + q];
            }
        }
        __syncthreads();

        if (tid < 2 * HH) {
            int mm = tid / HH, hh = tid - mm * HH;
            long row = (long)(m0 + mm) * LATM + t;
            float* g = gi + row * H3;
            float ir = gis[mm][hh], iz = gis[mm][HH + hh], inn = gis[mm][2 * HH + hh];
            float r  = sigm(ir + ghs[mm][hh]);
            float z  = sigm(iz + ghs[mm][HH + hh]);
            float nn = tanhf(inn + r * ghs[mm][2 * HH + hh]);
            float hn = (1.0f - z) * nn + z * hs[mm][hh];
            hs[mm][hh] = hn;
            g[hh] = hn;
        }
        __syncthreads();
    }
}

__global__ void mean_kernel(const float* __restrict__ ah, float* __restrict__ out)
{
    int idx = blockIdx.x * blockDim.x + threadIdx.x;
    if (idx >= MMOL * HH) return;
    int m = idx / HH;
    int j = idx - m * HH;
    long base = (long)m * LATM * HH + j;
    float s = 0.0f;
    for (int t = 0; t < LATM; ++t) s += ah[base + (long)t * HH];
    out[idx] = s * (1.0f / LATM);
}

// ---------------------------------------------------------------------------
static inline int cdiv(long a, long b) { return (int)((a + b - 1) / b); }

extern "C" void kernel_launch(void* const* d_in, const int* in_sizes, int n_in,
                              void* d_out, int out_size, void* d_ws, size_t ws_size,
                              hipStream_t stream)
{
    const float* f_atoms  = (const float*)d_in[0];
    const float* f_bonds  = (const float*)d_in[1];
    const int*   a2b      = (const int*)d_in[2];
    const int*   b2a      = (const int*)d_in[3];
    const int*   b2revb   = (const int*)d_in[4];
    const float* W_i_atom = (const float*)d_in[5];
    const float* W_i_bond = (const float*)d_in[6];
    const float* W_h0     = (const float*)d_in[7];
    const float* W_h1     = (const float*)d_in[8];
    const float* W_lr     = (const float*)d_in[9];
    const float* gru_bias = (const float*)d_in[10];
    const float* Wih_f    = (const float*)d_in[11];
    const float* Whh_f    = (const float*)d_in[12];
    const float* bih_f    = (const float*)d_in[13];
    const float* bhh_f    = (const float*)d_in[14];
    const float* Wih_b    = (const float*)d_in[15];
    const float* Whh_b    = (const float*)d_in[16];
    const float* bih_b    = (const float*)d_in[17];
    const float* bhh_b    = (const float*)d_in[18];
    const float* W_o      = (const float*)d_in[19];
    const float* b_o      = (const float*)d_in[20];
    float* out = (float*)d_out;

    const size_t NEED = 295530016;
    if (ws_size < NEED) return;

    char* b = (char*)d_ws;
    float* P   = (float*)b;
    float* S   = (float*)(b + 157287600);
    float* MA  = (float*)(b + 235931408);
    float* TH  = (float*)(b + 275254208);
    char*  TAIL = b + 294915616;              // 614,400 B spare

    float* Pia  = P + (size_t)AA * HH;        // ia_rc [A,300]
    float* giF  = (float*)b;                  // [ML,900]
    float* giB  = (float*)(b + 117964800);    // [ML,900]
    float* MSGX = MA;                         // [ML,300]
    float* AH   = MA;                         // atomhid [ML,300]
    float* H0   = TH;                         // [M,300]
    float* WQ_f = TH + 76800;                 // 270,000 floats
    float* WQ_b = TH + 346800;                // 270,000 floats

    // bf16 weight-plane buffers (TAIL time-shared: W_h / WiB / W_lr chunks)
    unsigned short* PL_IA = (unsigned short*)TAIL;
    unsigned short* PL_IB = (unsigned short*)(TAIL + 307200);
    unsigned short* PL_W  = (unsigned short*)TAIL;
    unsigned short* PL_B  = (unsigned short*)TAIL;
    char* THsp = ((char*)TH) + 2467200;
    unsigned short* PL_WIHF = (unsigned short*)THsp;
    unsigned short* PL_WIHB = (unsigned short*)(THsp + 1843200);
    unsigned short* PL_WO1  = (unsigned short*)TH;
    unsigned short* PL_WO2  = (unsigned short*)(((char*)TH) + 614400);

    dim3 blk(256);
    const int gA = cdiv((long)AA * HH, 256);
    const int spl_sm = cdiv(320 * 160, 256);
    const int spl_md = cdiv(320 * 320, 256);
    const int spl_lg = cdiv(960 * 320, 256);

    // ---- input projections ----
    split_w<<<spl_sm, blk, 0, stream>>>(W_i_atom, AFD, 0, 300, AFD, 320, 160, PL_IA);
    split_w<<<spl_sm, blk, 0, stream>>>(W_i_bond, BFD, 0, 300, BFD, 320, 160, PL_IB);
    mfma2<5, true, false, false><<<dim3(cdiv(AA, 64), 1), blk, 0, stream>>>(
        f_atoms, AFD, PL_IA, 0, 320, 160, nullptr, MA, HH, AA, HH, AFD);
    mfma2<5, true, false, false><<<dim3(cdiv(BBND, 64), 1), blk, 0, stream>>>(
        f_bonds, BFD, PL_IB, 0, 320, 160, nullptr, P, HH, BBND, HH, BFD);

    // ---- depth loop ----
    const float* Wh[2] = { W_h0, W_h1 };
    for (int d = 0; d < 2; ++d) {
        const float* W = Wh[d];
        aggregate<true><<<gA, blk, 0, stream>>>(P, a2b, MA);
        split_w<<<spl_md, blk, 0, stream>>>(W, HH, 0, 300, 300, 320, 320, PL_W);
        mfma_vw<<<dim3(cdiv(BBND, 64), 1), blk, 0, stream>>>(P, PL_W, S, P, BBND);
        mfma2<3, false, false, false><<<dim3(cdiv(AA, 64), 1), blk, 0, stream>>>(
            MA, HH, PL_W, 150, 320, 320, nullptr, TH, 150, AA, 150, HH);
        split_w<<<spl_sm, blk, 0, stream>>>(W_i_bond, BFD, 0, 300, BFD, 320, 160, PL_B);
        mfma_bond<3><<<dim3(cdiv(BBND, 64), 1), blk, 0, stream>>>(
            f_bonds, BFD, PL_B, 150, 320, 160, TH, P, 300, b2a, b2revb,
            P, 150, BBND, 150, BFD);
        split_w<<<spl_md, blk, 0, stream>>>(W, HH, 0, 300, 300, 320, 320, PL_W);
        mfma2<3, false, false, false><<<dim3(cdiv(AA, 64), 1), blk, 0, stream>>>(
            MA, HH, PL_W, 0, 320, 320, nullptr, TH, 150, AA, 150, HH);
        split_w<<<spl_sm, blk, 0, stream>>>(W_i_bond, BFD, 0, 300, BFD, 320, 160, PL_B);
        mfma_bond<3><<<dim3(cdiv(BBND, 64), 1), blk, 0, stream>>>(
            f_bonds, BFD, PL_B, 0, 320, 160, TH, S, 150, b2a, b2revb,
            P, 0, BBND, 150, BFD);
    }

    // Final aggregation -> S
    aggregate<false><<<gA, blk, 0, stream>>>(P, a2b, S);

    // ia recomputed -> Pia
    split_w<<<spl_sm, blk, 0, stream>>>(W_i_atom, AFD, 0, 300, AFD, 320, 160, PL_IA);
    mfma2<5, true, false, false><<<dim3(cdiv(AA, 64), 1), blk, 0, stream>>>(
        f_atoms, AFD, PL_IA, 0, 320, 160, nullptr, Pia, HH, AA, HH, AFD);

    // node = [agg|ma|ia] @ W_lr^T -> P (3 accumulating K-chunks)
    split_w<<<spl_md, blk, 0, stream>>>(W_lr, H3, 0, 300, 300, 320, 320, PL_W);
    mfma2<5, false, false, false><<<dim3(cdiv(AA, 64), 1), blk, 0, stream>>>(
        S, HH, PL_W, 0, 320, 320, nullptr, P, HH, AA, HH, HH);
    split_w<<<spl_md, blk, 0, stream>>>(W_lr, H3, HH, 300, 300, 320, 320, PL_W);
    mfma2<5, false, false, true><<<dim3(cdiv(AA, 64), 1), blk, 0, stream>>>(
        MA, HH, PL_W, 0, 320, 320, nullptr, P, HH, AA, HH, HH);
    split_w<<<spl_md, blk, 0, stream>>>(W_lr, H3, 2 * HH, 300, 300, 320, 320, PL_W);
    mfma2<5, false, false, true><<<dim3(cdiv(AA, 64), 1), blk, 0, stream>>>(
        Pia, HH, PL_W, 0, 320, 320, nullptr, P, HH, AA, HH, HH);

    // GRU prep
    msgx_kernel<<<cdiv((long)MLR * HH, 256), blk, 0, stream>>>(P, gru_bias, MSGX);
    h0_kernel<<<cdiv(MMOL * HH, 256), blk, 0, stream>>>(P, H0);
    transposeQ<<<cdiv(270000, 256), blk, 0, stream>>>(Whh_f, WQ_f);
    transposeQ<<<cdiv(270000, 256), blk, 0, stream>>>(Whh_b, WQ_b);

    // gi = msgx @ Wih^T + bih
    split_w<<<spl_lg, blk, 0, stream>>>(Wih_f, HH, 0, H3, 300, 960, 320, PL_WIHF);
    split_w<<<spl_lg, blk, 0, stream>>>(Wih_b, HH, 0, H3, 300, 960, 320, PL_WIHB);
    mfma2<5, false, true, false><<<dim3(cdiv(MLR, 64), 3), blk, 0, stream>>>(
        MSGX, HH, PL_WIHF, 0, 960, 320, bih_f, giF, H3, MLR, H3, HH);
    mfma2<5, false, true, false><<<dim3(cdiv(MLR, 64), 3), blk, 0, stream>>>(
        MSGX, HH, PL_WIHB, 0, 960, 320, bih_b, giB, H3, MLR, H3, HH);

    // Fused bidirectional scan (gi-prefetch variant)
    gru_scan3<<<dim3(256), dim3(1024), 0, stream>>>(
        WQ_f, bhh_f, WQ_b, bhh_b, H0, giF, giB);

    // atom_hiddens -> AH
    split_w<<<spl_md, blk, 0, stream>>>(W_o, 2 * HH, 0,  300, 300, 320, 320, PL_WO1);
    split_w<<<spl_md, blk, 0, stream>>>(W_o, 2 * HH, HH, 300, 300, 320, 320, PL_WO2);
    mfma2<5, false, false, false><<<dim3(cdiv(MLR, 64), 1), blk, 0, stream>>>(
        giF, H3, PL_WO1, 0, 320, 320, nullptr, AH, HH, MLR, HH, HH);
    mfma2<5, true, true, true><<<dim3(cdiv(MLR, 64), 1), blk, 0, stream>>>(
        giB, H3, PL_WO2, 0, 320, 320, b_o, AH, HH, MLR, HH, HH);

    // mol_vecs -> out
    mean_kernel<<<cdiv(MMOL * HH, 256), blk, 0, stream>>>(AH, out);
}

// Round 21
// 4688.554 us; speedup vs baseline: 1.0177x; 1.0177x over previous
//
#include <hip/hip_runtime.h>
#include <math.h>

// Problem constants
#define HH   300
#define H3   900
#define MMOL 256
#define LATM 128
#define AA   32769        // 1 + 256*128
#define NBB  6
#define BBND 131073       // 1 + 4*256*128
#define AFD  133
#define BFD  147
#define MLR  (MMOL * LATM)   // 32768

static __device__ __forceinline__ float sigm(float x) { return 1.0f / (1.0f + expf(-x)); }

typedef __attribute__((ext_vector_type(8))) short bfrag;   // 8 bf16
typedef __attribute__((ext_vector_type(4))) float ffrag;   // 4 f32

static __device__ __forceinline__ unsigned short f2bf(float x) {
    unsigned u = __float_as_uint(x);
    u += 0x7FFF + ((u >> 16) & 1);
    return (unsigned short)(u >> 16);
}
static __device__ __forceinline__ float bf2f(unsigned short h) {
    return __uint_as_float(((unsigned)h) << 16);
}

// ---------------------------------------------------------------------------
// split_w: W[N rows, k in koff..koff+K) of ldw-strided fp32 -> 3 bf16 planes
// ---------------------------------------------------------------------------
__global__ void split_w(const float* __restrict__ W, int ldw, int koff, int N, int K,
                        int Npad, int Kpad, unsigned short* __restrict__ planes)
{
    long tot = (long)Npad * Kpad;
    long idx = (long)blockIdx.x * blockDim.x + threadIdx.x;
    if (idx >= tot) return;
    int n = (int)(idx / Kpad), k = (int)(idx - (long)n * Kpad);
    float x = (n < N && k < K) ? W[(long)n * ldw + koff + k] : 0.0f;
    unsigned short h = f2bf(x); float r1 = x - bf2f(h);
    unsigned short m = f2bf(r1); float r2 = r1 - bf2f(m);
    planes[idx] = h;
    planes[tot + idx] = m;
    planes[2 * tot + idx] = f2bf(r2);
}

// ---------------------------------------------------------------------------
// mfma2: fp32-equivalent GEMM, 3-way bf16 split, 6 products (validated order).
// ---------------------------------------------------------------------------
template<int NCT, bool RELU, bool BIAS, bool ACCUM>
__global__ __launch_bounds__(256)
void mfma2(const float* __restrict__ X, int ldx,
           const unsigned short* __restrict__ Wpl, int wrow0, int Nalloc, int Kpad,
           const float* __restrict__ Bias, float* __restrict__ C, int ldc,
           int rows, int N, int K)
{
    __shared__ __align__(16) unsigned short Xp[3][64][40];
    const int tid  = threadIdx.x;
    const int lane = tid & 63;
    const int wv   = tid >> 6;
    const int row0 = blockIdx.x * 64;
    const int colbase = blockIdx.y * (NCT * 64);
    const int wr   = (wv >> 1) * 32;
    const int wc   = (wv & 1) * 32;
    const int sr   = tid >> 2;
    const int sk   = (tid & 3) * 8;
    const long PS  = (long)Nalloc * Kpad;

    ffrag acc[NCT][2][2];
#pragma unroll
    for (int c = 0; c < NCT; ++c)
#pragma unroll
        for (int i = 0; i < 2; ++i)
#pragma unroll
            for (int j = 0; j < 2; ++j) acc[c][i][j] = (ffrag){0.f, 0.f, 0.f, 0.f};

    const int fr = lane & 15;
    const int kb = (lane >> 4) * 8;

    for (int k0 = 0; k0 < K; k0 += 32) {
        {
            unsigned short h8[8], m8[8], l8[8];
            int gr = row0 + sr;
#pragma unroll
            for (int i = 0; i < 8; ++i) {
                int k = k0 + sk + i;
                float x = (gr < rows && k < K) ? X[(long)gr * ldx + k] : 0.0f;
                unsigned short h = f2bf(x); float r1 = x - bf2f(h);
                unsigned short m = f2bf(r1); float r2 = r1 - bf2f(m);
                h8[i] = h; m8[i] = m; l8[i] = f2bf(r2);
            }
            *(bfrag*)&Xp[0][sr][sk] = *(bfrag*)h8;
            *(bfrag*)&Xp[1][sr][sk] = *(bfrag*)m8;
            *(bfrag*)&Xp[2][sr][sk] = *(bfrag*)l8;
        }
        __syncthreads();

        bfrag ax[3][2];
#pragma unroll
        for (int s = 0; s < 3; ++s)
#pragma unroll
            for (int t2 = 0; t2 < 2; ++t2)
                ax[s][t2] = *(const bfrag*)&Xp[s][wr + t2 * 16 + fr][kb];

#pragma unroll
        for (int ct = 0; ct < NCT; ++ct) {
            int prow0 = wrow0 + colbase + ct * 64 + wc + fr;
            int pr[2];
            pr[0] = prow0;              if (pr[0] > Nalloc - 1) pr[0] = Nalloc - 1;
            pr[1] = prow0 + 16;         if (pr[1] > Nalloc - 1) pr[1] = Nalloc - 1;
            bfrag bx[3][2];
#pragma unroll
            for (int s = 0; s < 3; ++s)
#pragma unroll
                for (int t2 = 0; t2 < 2; ++t2)
                    bx[s][t2] = *(const bfrag*)(Wpl + (long)s * PS + (long)pr[t2] * Kpad + k0 + kb);

#pragma unroll
            for (int st = 0; st < 2; ++st)
#pragma unroll
                for (int c2 = 0; c2 < 2; ++c2) {
                    ffrag a = acc[ct][st][c2];
                    a = __builtin_amdgcn_mfma_f32_16x16x32_bf16(ax[1][st], bx[1][c2], a, 0, 0, 0); // mM
                    a = __builtin_amdgcn_mfma_f32_16x16x32_bf16(ax[0][st], bx[2][c2], a, 0, 0, 0); // hL
                    a = __builtin_amdgcn_mfma_f32_16x16x32_bf16(ax[2][st], bx[0][c2], a, 0, 0, 0); // lH
                    a = __builtin_amdgcn_mfma_f32_16x16x32_bf16(ax[0][st], bx[1][c2], a, 0, 0, 0); // hM
                    a = __builtin_amdgcn_mfma_f32_16x16x32_bf16(ax[1][st], bx[0][c2], a, 0, 0, 0); // mH
                    a = __builtin_amdgcn_mfma_f32_16x16x32_bf16(ax[0][st], bx[0][c2], a, 0, 0, 0); // hH
                    acc[ct][st][c2] = a;
                }
        }
        __syncthreads();
    }

    const int orow = (lane >> 4) * 4;
    const int ocol = lane & 15;
#pragma unroll
    for (int ct = 0; ct < NCT; ++ct)
#pragma unroll
        for (int st = 0; st < 2; ++st)
#pragma unroll
            for (int c2 = 0; c2 < 2; ++c2)
#pragma unroll
                for (int rg = 0; rg < 4; ++rg) {
                    int gr = row0 + wr + st * 16 + orow + rg;
                    int gc = colbase + ct * 64 + wc + c2 * 16 + ocol;
                    if (gr < rows && gc < N) {
                        float v = acc[ct][st][c2][rg];
                        if (BIAS)  v += Bias[gc];
                        if (ACCUM) v += C[(long)gr * ldc + gc];
                        if (RELU)  v = fmaxf(v, 0.0f);
                        C[(long)gr * ldc + gc] = v;
                    }
                }
}

// ---------------------------------------------------------------------------
// mfma_vw: merged Vw (lo -> S, hi -> P in place), bit-identical split/order.
// ---------------------------------------------------------------------------
__global__ __launch_bounds__(256)
void mfma_vw(const float* __restrict__ Xp_, const unsigned short* __restrict__ Wpl,
             float* __restrict__ S, float* __restrict__ P, int rows)
{
    const int NCT = 5;
    __shared__ __align__(16) unsigned short Xp[3][64][40];
    const int tid  = threadIdx.x;
    const int lane = tid & 63;
    const int wv   = tid >> 6;
    const int row0 = blockIdx.x * 64;
    const int wr   = (wv >> 1) * 32;
    const int wc   = (wv & 1) * 32;
    const int sr   = tid >> 2;
    const int sk   = (tid & 3) * 8;
    const long PS  = (long)320 * 320;

    ffrag acc[NCT][2][2];
#pragma unroll
    for (int c = 0; c < NCT; ++c)
#pragma unroll
        for (int i = 0; i < 2; ++i)
#pragma unroll
            for (int j = 0; j < 2; ++j) acc[c][i][j] = (ffrag){0.f, 0.f, 0.f, 0.f};

    const int fr = lane & 15;
    const int kb = (lane >> 4) * 8;

    for (int k0 = 0; k0 < 300; k0 += 32) {
        {
            unsigned short h8[8], m8[8], l8[8];
            int gr = row0 + sr;
#pragma unroll
            for (int i = 0; i < 8; ++i) {
                int k = k0 + sk + i;
                float x = (gr < rows && k < 300) ? Xp_[(long)gr * 300 + k] : 0.0f;
                unsigned short h = f2bf(x); float r1 = x - bf2f(h);
                unsigned short m = f2bf(r1); float r2 = r1 - bf2f(m);
                h8[i] = h; m8[i] = m; l8[i] = f2bf(r2);
            }
            *(bfrag*)&Xp[0][sr][sk] = *(bfrag*)h8;
            *(bfrag*)&Xp[1][sr][sk] = *(bfrag*)m8;
            *(bfrag*)&Xp[2][sr][sk] = *(bfrag*)l8;
        }
        __syncthreads();

        bfrag ax[3][2];
#pragma unroll
        for (int s = 0; s < 3; ++s)
#pragma unroll
            for (int t2 = 0; t2 < 2; ++t2)
                ax[s][t2] = *(const bfrag*)&Xp[s][wr + t2 * 16 + fr][kb];

#pragma unroll
        for (int ct = 0; ct < NCT; ++ct) {
            int prow0 = ct * 64 + wc + fr;
            int pr[2];
            pr[0] = prow0;       if (pr[0] > 319) pr[0] = 319;
            pr[1] = prow0 + 16;  if (pr[1] > 319) pr[1] = 319;
            bfrag bx[3][2];
#pragma unroll
            for (int s = 0; s < 3; ++s)
#pragma unroll
                for (int t2 = 0; t2 < 2; ++t2)
                    bx[s][t2] = *(const bfrag*)(Wpl + (long)s * PS + (long)pr[t2] * 320 + k0 + kb);

#pragma unroll
            for (int st = 0; st < 2; ++st)
#pragma unroll
                for (int c2 = 0; c2 < 2; ++c2) {
                    ffrag a = acc[ct][st][c2];
                    a = __builtin_amdgcn_mfma_f32_16x16x32_bf16(ax[1][st], bx[1][c2], a, 0, 0, 0);
                    a = __builtin_amdgcn_mfma_f32_16x16x32_bf16(ax[0][st], bx[2][c2], a, 0, 0, 0);
                    a = __builtin_amdgcn_mfma_f32_16x16x32_bf16(ax[2][st], bx[0][c2], a, 0, 0, 0);
                    a = __builtin_amdgcn_mfma_f32_16x16x32_bf16(ax[0][st], bx[1][c2], a, 0, 0, 0);
                    a = __builtin_amdgcn_mfma_f32_16x16x32_bf16(ax[1][st], bx[0][c2], a, 0, 0, 0);
                    a = __builtin_amdgcn_mfma_f32_16x16x32_bf16(ax[0][st], bx[0][c2], a, 0, 0, 0);
                    acc[ct][st][c2] = a;
                }
        }
        __syncthreads();
    }

    const int orow = (lane >> 4) * 4;
    const int ocol = lane & 15;
#pragma unroll
    for (int ct = 0; ct < NCT; ++ct)
#pragma unroll
        for (int st = 0; st < 2; ++st)
#pragma unroll
            for (int c2 = 0; c2 < 2; ++c2)
#pragma unroll
                for (int rg = 0; rg < 4; ++rg) {
                    int gr = row0 + wr + st * 16 + orow + rg;
                    int gc = ct * 64 + wc + c2 * 16 + ocol;
                    if (gr < rows && gc < 300) {
                        float v = acc[ct][st][c2][rg];
                        if (gc < 150) S[(long)gr * 150 + gc] = v;
                        else          P[(long)gr * 300 + (gc - 150)] = v;
                    }
                }
}

// ---------------------------------------------------------------------------
// mfma_bond: mfma2 core (X = f_bonds, K=147) + gather epilogue.
// ---------------------------------------------------------------------------
template<int NCT>
__global__ __launch_bounds__(256)
void mfma_bond(const float* __restrict__ X, int ldx,
               const unsigned short* __restrict__ Wpl, int wrow0, int Nalloc, int Kpad,
               const float* __restrict__ Th, const float* __restrict__ Vsrc, int vstride,
               const int* __restrict__ b2a, const int* __restrict__ b2revb,
               float* __restrict__ P, int c0, int rows, int N, int K)
{
    __shared__ __align__(16) unsigned short Xp[3][64][40];
    const int tid  = threadIdx.x;
    const int lane = tid & 63;
    const int wv   = tid >> 6;
    const int row0 = blockIdx.x * 64;
    const int colbase = blockIdx.y * (NCT * 64);
    const int wr   = (wv >> 1) * 32;
    const int wc   = (wv & 1) * 32;
    const int sr   = tid >> 2;
    const int sk   = (tid & 3) * 8;
    const long PS  = (long)Nalloc * Kpad;

    ffrag acc[NCT][2][2];
#pragma unroll
    for (int c = 0; c < NCT; ++c)
#pragma unroll
        for (int i = 0; i < 2; ++i)
#pragma unroll
            for (int j = 0; j < 2; ++j) acc[c][i][j] = (ffrag){0.f, 0.f, 0.f, 0.f};

    const int fr = lane & 15;
    const int kb = (lane >> 4) * 8;

    for (int k0 = 0; k0 < K; k0 += 32) {
        {
            unsigned short h8[8], m8[8], l8[8];
            int gr = row0 + sr;
#pragma unroll
            for (int i = 0; i < 8; ++i) {
                int k = k0 + sk + i;
                float x = (gr < rows && k < K) ? X[(long)gr * ldx + k] : 0.0f;
                unsigned short h = f2bf(x); float r1 = x - bf2f(h);
                unsigned short m = f2bf(r1); float r2 = r1 - bf2f(m);
                h8[i] = h; m8[i] = m; l8[i] = f2bf(r2);
            }
            *(bfrag*)&Xp[0][sr][sk] = *(bfrag*)h8;
            *(bfrag*)&Xp[1][sr][sk] = *(bfrag*)m8;
            *(bfrag*)&Xp[2][sr][sk] = *(bfrag*)l8;
        }
        __syncthreads();

        bfrag ax[3][2];
#pragma unroll
        for (int s = 0; s < 3; ++s)
#pragma unroll
            for (int t2 = 0; t2 < 2; ++t2)
                ax[s][t2] = *(const bfrag*)&Xp[s][wr + t2 * 16 + fr][kb];

#pragma unroll
        for (int ct = 0; ct < NCT; ++ct) {
            int prow0 = wrow0 + colbase + ct * 64 + wc + fr;
            int pr[2];
            pr[0] = prow0;              if (pr[0] > Nalloc - 1) pr[0] = Nalloc - 1;
            pr[1] = prow0 + 16;         if (pr[1] > Nalloc - 1) pr[1] = Nalloc - 1;
            bfrag bx[3][2];
#pragma unroll
            for (int s = 0; s < 3; ++s)
#pragma unroll
                for (int t2 = 0; t2 < 2; ++t2)
                    bx[s][t2] = *(const bfrag*)(Wpl + (long)s * PS + (long)pr[t2] * Kpad + k0 + kb);

#pragma unroll
            for (int st = 0; st < 2; ++st)
#pragma unroll
                for (int c2 = 0; c2 < 2; ++c2) {
                    ffrag a = acc[ct][st][c2];
                    a = __builtin_amdgcn_mfma_f32_16x16x32_bf16(ax[1][st], bx[1][c2], a, 0, 0, 0);
                    a = __builtin_amdgcn_mfma_f32_16x16x32_bf16(ax[0][st], bx[2][c2], a, 0, 0, 0);
                    a = __builtin_amdgcn_mfma_f32_16x16x32_bf16(ax[2][st], bx[0][c2], a, 0, 0, 0);
                    a = __builtin_amdgcn_mfma_f32_16x16x32_bf16(ax[0][st], bx[1][c2], a, 0, 0, 0);
                    a = __builtin_amdgcn_mfma_f32_16x16x32_bf16(ax[1][st], bx[0][c2], a, 0, 0, 0);
                    a = __builtin_amdgcn_mfma_f32_16x16x32_bf16(ax[0][st], bx[0][c2], a, 0, 0, 0);
                    acc[ct][st][c2] = a;
                }
        }
        __syncthreads();
    }

    const int orow = (lane >> 4) * 4;
    const int ocol = lane & 15;
#pragma unroll
    for (int st = 0; st < 2; ++st)
#pragma unroll
        for (int rg = 0; rg < 4; ++rg) {
            int gr = row0 + wr + st * 16 + orow + rg;
            if (gr >= rows) continue;
            int a  = b2a[gr];
            int rv = b2revb[gr];
#pragma unroll
            for (int ct = 0; ct < NCT; ++ct)
#pragma unroll
                for (int c2 = 0; c2 < 2; ++c2) {
                    int gc = colbase + ct * 64 + wc + c2 * 16 + ocol;
                    if (gc >= N) continue;
                    float ib = fmaxf(acc[ct][st][c2][rg], 0.0f);
                    float v  = ib + Th[(long)a * 150 + gc] - Vsrc[(long)rv * vstride + gc];
                    P[(long)gr * 300 + c0 + gc] = fmaxf(v, 0.0f);
                }
        }
}

// transposeQ: Whh[900][300] -> WQ[(k/4)][n][4]
__global__ void transposeQ(const float* __restrict__ in, float* __restrict__ out)
{
    long idx = (long)blockIdx.x * blockDim.x + threadIdx.x;
    if (idx >= 270000) return;
    int n = (int)(idx / 300), k = (int)(idx - (long)n * 300);
    out[(long)(k >> 2) * 3600 + n * 4 + (k & 3)] = in[idx];
}

template<bool ADD>
__global__ void aggregate(const float* __restrict__ mb, const int* __restrict__ a2b,
                          float* __restrict__ dst)
{
    long idx = (long)blockIdx.x * blockDim.x + threadIdx.x;
    if (idx >= (long)AA * HH) return;
    int a = (int)(idx / HH);
    int h = (int)(idx - (long)a * HH);
    const int* nb = a2b + (long)a * NBB;
    float s = 0.0f, mx = -INFINITY;
#pragma unroll
    for (int i = 0; i < NBB; ++i) {
        float v = mb[(long)nb[i] * HH + h];
        s += v;
        mx = fmaxf(mx, v);
    }
    float r = s * mx;
    if (ADD) r += dst[idx];
    dst[idx] = r;
}

__global__ void msgx_kernel(const float* __restrict__ node, const float* __restrict__ gbias,
                            float* __restrict__ msgx)
{
    long idx = (long)blockIdx.x * blockDim.x + threadIdx.x;
    if (idx >= (long)MLR * HH) return;
    int h = (int)(idx % HH);
    msgx[idx] = fmaxf(node[idx + HH] + gbias[h], 0.0f);
}

__global__ void h0_kernel(const float* __restrict__ node, float* __restrict__ hf)
{
    int idx = blockIdx.x * blockDim.x + threadIdx.x;
    if (idx >= MMOL * HH) return;
    int m = idx / HH;
    int h = idx - m * HH;
    long base = (long)(1 + m * LATM) * HH + h;
    float mx = -INFINITY;
    for (int t = 0; t < LATM; ++t) mx = fmaxf(mx, node[base + (long)t * HH]);
    hf[idx] = mx;
}

// ---------------------------------------------------------------------------
// GRU scan v3q (proven round-19 version, reverted verbatim)
// ---------------------------------------------------------------------------
__global__ __launch_bounds__(1024)
void gru_scan3(const float* __restrict__ WQ_f, const float* __restrict__ bhh_f,
               const float* __restrict__ WQ_b, const float* __restrict__ bhh_b,
               const float* __restrict__ h0, float* __restrict__ gi_f,
               float* __restrict__ gi_b)
{
    const int bid  = blockIdx.x;
    const int xcd  = bid & 7;
    const int dir  = (xcd >= 4) ? 1 : 0;
    const int rank = (bid >> 3) * 4 + (xcd & 3);
    const int m0   = rank * 2;
    const float* WQ  = dir ? WQ_b  : WQ_f;
    const float* bhh = dir ? bhh_b : bhh_f;
    float*       gi  = dir ? gi_b  : gi_f;
    const int tid = threadIdx.x;

    __shared__ float hs[2][304];
    __shared__ float ghs[2][H3];

    float bb = (tid < H3) ? bhh[tid] : 0.0f;

    for (int i = tid; i < 150; i += 1024) {
        int mm = i / 75, q = (i - mm * 75) * 4;
        *(float4*)&hs[mm][q] = *(const float4*)&h0[(long)(m0 + mm) * HH + q];
    }
    __syncthreads();

    for (int s = 0; s < LATM; ++s) {
        const int t = dir ? (LATM - 1 - s) : s;

        if (tid < H3) {
            float a0 = 0.0f, a1 = 0.0f;
            const float* wq = WQ + (long)tid * 4;
#pragma unroll 4
            for (int k0 = 0; k0 < HH; k0 += 4) {
                float4 w = *(const float4*)wq;
                wq += 3600;
                float4 h0v = *(const float4*)&hs[0][k0];
                float4 h1v = *(const float4*)&hs[1][k0];
                a0 += h0v.x * w.x + h0v.y * w.y + h0v.z * w.z + h0v.w * w.w;
                a1 += h1v.x * w.x + h1v.y * w.y + h1v.z * w.z + h1v.w * w.w;
            }
            ghs[0][tid] = a0 + bb;
            ghs[1][tid] = a1 + bb;
        }
        __syncthreads();

        if (tid < 2 * HH) {
            int mm = tid / HH, hh = tid - mm * HH;
            long row = (long)(m0 + mm) * LATM + t;
            float* g = gi + row * H3;
            float ir = g[hh], iz = g[HH + hh], inn = g[2 * HH + hh];
            float r  = sigm(ir + ghs[mm][hh]);
            float z  = sigm(iz + ghs[mm][HH + hh]);
            float nn = tanhf(inn + r * ghs[mm][2 * HH + hh]);
            float hn = (1.0f - z) * nn + z * hs[mm][hh];
            hs[mm][hh] = hn;
            g[hh] = hn;
        }
        __syncthreads();
    }
}

__global__ void mean_kernel(const float* __restrict__ ah, float* __restrict__ out)
{
    int idx = blockIdx.x * blockDim.x + threadIdx.x;
    if (idx >= MMOL * HH) return;
    int m = idx / HH;
    int j = idx - m * HH;
    long base = (long)m * LATM * HH + j;
    float s = 0.0f;
    for (int t = 0; t < LATM; ++t) s += ah[base + (long)t * HH];
    out[idx] = s * (1.0f / LATM);
}

// ---------------------------------------------------------------------------
static inline int cdiv(long a, long b) { return (int)((a + b - 1) / b); }

extern "C" void kernel_launch(void* const* d_in, const int* in_sizes, int n_in,
                              void* d_out, int out_size, void* d_ws, size_t ws_size,
                              hipStream_t stream)
{
    const float* f_atoms  = (const float*)d_in[0];
    const float* f_bonds  = (const float*)d_in[1];
    const int*   a2b      = (const int*)d_in[2];
    const int*   b2a      = (const int*)d_in[3];
    const int*   b2revb   = (const int*)d_in[4];
    const float* W_i_atom = (const float*)d_in[5];
    const float* W_i_bond = (const float*)d_in[6];
    const float* W_h0     = (const float*)d_in[7];
    const float* W_h1     = (const float*)d_in[8];
    const float* W_lr     = (const float*)d_in[9];
    const float* gru_bias = (const float*)d_in[10];
    const float* Wih_f    = (const float*)d_in[11];
    const float* Whh_f    = (const float*)d_in[12];
    const float* bih_f    = (const float*)d_in[13];
    const float* bhh_f    = (const float*)d_in[14];
    const float* Wih_b    = (const float*)d_in[15];
    const float* Whh_b    = (const float*)d_in[16];
    const float* bih_b    = (const float*)d_in[17];
    const float* bhh_b    = (const float*)d_in[18];
    const float* W_o      = (const float*)d_in[19];
    const float* b_o      = (const float*)d_in[20];
    float* out = (float*)d_out;

    const size_t NEED = 295530016;
    if (ws_size < NEED) return;

    char* b = (char*)d_ws;
    float* P   = (float*)b;
    float* S   = (float*)(b + 157287600);
    float* MA  = (float*)(b + 235931408);
    float* TH  = (float*)(b + 275254208);
    char*  TAIL = b + 294915616;              // 614,400 B spare

    float* Pia  = P + (size_t)AA * HH;        // ia_rc [A,300]
    float* giF  = (float*)b;                  // [ML,900]
    float* giB  = (float*)(b + 117964800);    // [ML,900]
    float* MSGX = MA;                         // [ML,300]
    float* AH   = MA;                         // atomhid [ML,300]
    float* H0   = TH;                         // [M,300]
    float* WQ_f = TH + 76800;                 // 270,000 floats
    float* WQ_b = TH + 346800;                // 270,000 floats

    // bf16 weight-plane buffers (TAIL time-shared: W_h / WiB / W_lr chunks)
    unsigned short* PL_IA = (unsigned short*)TAIL;
    unsigned short* PL_IB = (unsigned short*)(TAIL + 307200);
    unsigned short* PL_W  = (unsigned short*)TAIL;
    unsigned short* PL_B  = (unsigned short*)TAIL;
    char* THsp = ((char*)TH) + 2467200;
    unsigned short* PL_WIHF = (unsigned short*)THsp;
    unsigned short* PL_WIHB = (unsigned short*)(THsp + 1843200);
    unsigned short* PL_WO1  = (unsigned short*)TH;
    unsigned short* PL_WO2  = (unsigned short*)(((char*)TH) + 614400);

    dim3 blk(256);
    const int gA = cdiv((long)AA * HH, 256);
    const int spl_sm = cdiv(320 * 160, 256);
    const int spl_md = cdiv(320 * 320, 256);
    const int spl_lg = cdiv(960 * 320, 256);

    // ---- input projections ----
    split_w<<<spl_sm, blk, 0, stream>>>(W_i_atom, AFD, 0, 300, AFD, 320, 160, PL_IA);
    split_w<<<spl_sm, blk, 0, stream>>>(W_i_bond, BFD, 0, 300, BFD, 320, 160, PL_IB);
    mfma2<5, true, false, false><<<dim3(cdiv(AA, 64), 1), blk, 0, stream>>>(
        f_atoms, AFD, PL_IA, 0, 320, 160, nullptr, MA, HH, AA, HH, AFD);
    mfma2<5, true, false, false><<<dim3(cdiv(BBND, 64), 1), blk, 0, stream>>>(
        f_bonds, BFD, PL_IB, 0, 320, 160, nullptr, P, HH, BBND, HH, BFD);

    // ---- depth loop ----
    const float* Wh[2] = { W_h0, W_h1 };
    for (int d = 0; d < 2; ++d) {
        const float* W = Wh[d];
        aggregate<true><<<gA, blk, 0, stream>>>(P, a2b, MA);
        split_w<<<spl_md, blk, 0, stream>>>(W, HH, 0, 300, 300, 320, 320, PL_W);
        mfma_vw<<<dim3(cdiv(BBND, 64), 1), blk, 0, stream>>>(P, PL_W, S, P, BBND);
        mfma2<3, false, false, false><<<dim3(cdiv(AA, 64), 1), blk, 0, stream>>>(
            MA, HH, PL_W, 150, 320, 320, nullptr, TH, 150, AA, 150, HH);
        split_w<<<spl_sm, blk, 0, stream>>>(W_i_bond, BFD, 0, 300, BFD, 320, 160, PL_B);
        mfma_bond<3><<<dim3(cdiv(BBND, 64), 1), blk, 0, stream>>>(
            f_bonds, BFD, PL_B, 150, 320, 160, TH, P, 300, b2a, b2revb,
            P, 150, BBND, 150, BFD);
        split_w<<<spl_md, blk, 0, stream>>>(W, HH, 0, 300, 300, 320, 320, PL_W);
        mfma2<3, false, false, false><<<dim3(cdiv(AA, 64), 1), blk, 0, stream>>>(
            MA, HH, PL_W, 0, 320, 320, nullptr, TH, 150, AA, 150, HH);
        split_w<<<spl_sm, blk, 0, stream>>>(W_i_bond, BFD, 0, 300, BFD, 320, 160, PL_B);
        mfma_bond<3><<<dim3(cdiv(BBND, 64), 1), blk, 0, stream>>>(
            f_bonds, BFD, PL_B, 0, 320, 160, TH, S, 150, b2a, b2revb,
            P, 0, BBND, 150, BFD);
    }

    // Final aggregation -> S
    aggregate<false><<<gA, blk, 0, stream>>>(P, a2b, S);

    // ia recomputed -> Pia
    split_w<<<spl_sm, blk, 0, stream>>>(W_i_atom, AFD, 0, 300, AFD, 320, 160, PL_IA);
    mfma2<5, true, false, false><<<dim3(cdiv(AA, 64), 1), blk, 0, stream>>>(
        f_atoms, AFD, PL_IA, 0, 320, 160, nullptr, Pia, HH, AA, HH, AFD);

    // node = [agg|ma|ia] @ W_lr^T -> P (3 accumulating K-chunks)
    split_w<<<spl_md, blk, 0, stream>>>(W_lr, H3, 0, 300, 300, 320, 320, PL_W);
    mfma2<5, false, false, false><<<dim3(cdiv(AA, 64), 1), blk, 0, stream>>>(
        S, HH, PL_W, 0, 320, 320, nullptr, P, HH, AA, HH, HH);
    split_w<<<spl_md, blk, 0, stream>>>(W_lr, H3, HH, 300, 300, 320, 320, PL_W);
    mfma2<5, false, false, true><<<dim3(cdiv(AA, 64), 1), blk, 0, stream>>>(
        MA, HH, PL_W, 0, 320, 320, nullptr, P, HH, AA, HH, HH);
    split_w<<<spl_md, blk, 0, stream>>>(W_lr, H3, 2 * HH, 300, 300, 320, 320, PL_W);
    mfma2<5, false, false, true><<<dim3(cdiv(AA, 64), 1), blk, 0, stream>>>(
        Pia, HH, PL_W, 0, 320, 320, nullptr, P, HH, AA, HH, HH);

    // GRU prep
    msgx_kernel<<<cdiv((long)MLR * HH, 256), blk, 0, stream>>>(P, gru_bias, MSGX);
    h0_kernel<<<cdiv(MMOL * HH, 256), blk, 0, stream>>>(P, H0);
    transposeQ<<<cdiv(270000, 256), blk, 0, stream>>>(Whh_f, WQ_f);
    transposeQ<<<cdiv(270000, 256), blk, 0, stream>>>(Whh_b, WQ_b);

    // gi = msgx @ Wih^T + bih
    split_w<<<spl_lg, blk, 0, stream>>>(Wih_f, HH, 0, H3, 300, 960, 320, PL_WIHF);
    split_w<<<spl_lg, blk, 0, stream>>>(Wih_b, HH, 0, H3, 300, 960, 320, PL_WIHB);
    mfma2<5, false, true, false><<<dim3(cdiv(MLR, 64), 3), blk, 0, stream>>>(
        MSGX, HH, PL_WIHF, 0, 960, 320, bih_f, giF, H3, MLR, H3, HH);
    mfma2<5, false, true, false><<<dim3(cdiv(MLR, 64), 3), blk, 0, stream>>>(
        MSGX, HH, PL_WIHB, 0, 960, 320, bih_b, giB, H3, MLR, H3, HH);

    // Fused bidirectional scan
    gru_scan3<<<dim3(256), dim3(1024), 0, stream>>>(
        WQ_f, bhh_f, WQ_b, bhh_b, H0, giF, giB);

    // atom_hiddens -> AH
    split_w<<<spl_md, blk, 0, stream>>>(W_o, 2 * HH, 0,  300, 300, 320, 320, PL_WO1);
    split_w<<<spl_md, blk, 0, stream>>>(W_o, 2 * HH, HH, 300, 300, 320, 320, PL_WO2);
    mfma2<5, false, false, false><<<dim3(cdiv(MLR, 64), 1), blk, 0, stream>>>(
        giF, H3, PL_WO1, 0, 320, 320, nullptr, AH, HH, MLR, HH, HH);
    mfma2<5, true, true, true><<<dim3(cdiv(MLR, 64), 1), blk, 0, stream>>>(
        giB, H3, PL_WO2, 0, 320, 320, b_o, AH, HH, MLR, HH, HH);

    // mol_vecs -> out
    mean_kernel<<<cdiv(MMOL * HH, 256), blk, 0, stream>>>(AH, out);
}